// Round 1
// baseline (10649.104 us; speedup 1.0000x reference)
//
#include <hip/hip_runtime.h>

// EncoderDecoderLSTM fused persistent kernel for MI355X (gfx950).
// B=8192 rows, H=64, T=336 encoder steps, 168 decoder steps.
// 256 blocks x 256 threads; each block owns 32 batch rows for the whole
// sequence. h/c state: c in registers, h in LDS. Weights streamed from L2
// through two ping-pong LDS tiles (68KB each) every step.

#define NB   256          // blocks
#define NT   256          // threads per block
#define TT   336          // encoder timesteps
#define HZN  168          // decoder horizon
#define MP   68           // padded LDS row stride (floats), 68*4B = 17*16B
#define WTILE (256*MP)    // one weight tile: 256 rows x MP floats
#define HBUFN (32*MP)     // h buffer: 32 rows x MP floats

__device__ __forceinline__ float fexp(float v){
  return __builtin_amdgcn_exp2f(v * 1.44269504088896340736f);
}
__device__ __forceinline__ float sigm(float v){
  return __builtin_amdgcn_rcpf(1.0f + fexp(-v));
}
__device__ __forceinline__ float tanh_(float v){
  return 1.0f - 2.0f * __builtin_amdgcn_rcpf(1.0f + fexp(2.0f * v));
}

// acc[t][ri][kh]: gate type t (i,f,g,o), row r4+ri, k-col kk+32*kh
__device__ __forceinline__ void acc_init(float a[4][4][2], const float b[4][2]){
  #pragma unroll
  for (int t=0;t<4;t++)
    #pragma unroll
    for (int ri=0;ri<4;ri++)
      #pragma unroll
      for (int kh=0;kh<2;kh++)
        a[t][ri][kh] = b[t][kh];
}

// accumulate a += in[4 rows][m0..m0+32) * W[gate rows][m0..m0+32)
__device__ __forceinline__ void mm32(const float* __restrict__ Wt,
                                     const float* __restrict__ inb,
                                     int kk, int r4, float a[4][4][2], int m0)
{
  const float* wb = Wt + kk*MP + m0;
  const float* ib = inb + r4*MP + m0;
  #pragma unroll 2
  for (int m=0;m<32;m+=4){
    float4 q[4];
    #pragma unroll
    for (int ri=0;ri<4;ri++)
      q[ri] = *reinterpret_cast<const float4*>(ib + ri*MP + m);
    #pragma unroll
    for (int t=0;t<4;t++){
      #pragma unroll
      for (int kh=0;kh<2;kh++){
        float4 w = *reinterpret_cast<const float4*>(wb + (t*64 + kh*32)*MP + m);
        #pragma unroll
        for (int ri=0;ri<4;ri++){
          a[t][ri][kh] = fmaf(w.x, q[ri].x, a[t][ri][kh]);
          a[t][ri][kh] = fmaf(w.y, q[ri].y, a[t][ri][kh]);
          a[t][ri][kh] = fmaf(w.z, q[ri].z, a[t][ri][kh]);
          a[t][ri][kh] = fmaf(w.w, q[ri].w, a[t][ri][kh]);
        }
      }
    }
  }
}

// stream 8 float4 granules of a [256][64] matrix: issue loads early...
__device__ __forceinline__ void stage8_issue(const float* __restrict__ src,
                                             int tid, int i0, float4 st[8]){
  #pragma unroll
  for (int i=0;i<8;i++){
    int g = ((i0+i)<<8) + tid;
    st[i] = *reinterpret_cast<const float4*>(src + g*4);
  }
}
// ...and write them into the padded LDS tile after the compute phase.
__device__ __forceinline__ void stage8_write(float* __restrict__ dst,
                                             int tid, int i0, const float4 st[8]){
  #pragma unroll
  for (int i=0;i<8;i++){
    int g = ((i0+i)<<8) + tid;
    *reinterpret_cast<float4*>(dst + (g>>4)*MP + (g&15)*4) = st[i];
  }
}

__device__ __forceinline__ void lstm_update(const float a[4][4][2],
                                            float c[4][2], float hv[4][2]){
  #pragma unroll
  for (int ri=0;ri<4;ri++)
    #pragma unroll
    for (int kh=0;kh<2;kh++){
      float ig = sigm(a[0][ri][kh]);
      float fg = sigm(a[1][ri][kh]);
      float gg = tanh_(a[2][ri][kh]);
      float og = sigm(a[3][ri][kh]);
      float cn = fmaf(fg, c[ri][kh], ig*gg);
      c[ri][kh] = cn;
      hv[ri][kh] = og * tanh_(cn);
    }
}

__device__ __forceinline__ void hwrite(float* __restrict__ hb, int r4, int kk,
                                       const float hv[4][2]){
  #pragma unroll
  for (int ri=0;ri<4;ri++){
    hb[(r4+ri)*MP + kk]      = hv[ri][0];
    hb[(r4+ri)*MP + kk + 32] = hv[ri][1];
  }
}

__global__ __launch_bounds__(NT, 1)
void edlstm_kernel(const float* __restrict__ x,
  const float* __restrict__ eWih0, const float* __restrict__ eWhh0,
  const float* __restrict__ ebih0, const float* __restrict__ ebhh0,
  const float* __restrict__ eWih1, const float* __restrict__ eWhh1,
  const float* __restrict__ ebih1, const float* __restrict__ ebhh1,
  const float* __restrict__ dWih0, const float* __restrict__ dWhh0,
  const float* __restrict__ dbih0, const float* __restrict__ dbhh0,
  const float* __restrict__ dWih1, const float* __restrict__ dWhh1,
  const float* __restrict__ dbih1, const float* __restrict__ dbhh1,
  const float* __restrict__ fcW, const float* __restrict__ fcb,
  float* __restrict__ out)
{
  extern __shared__ float sm[];
  float* bufA = sm;
  float* bufB = sm + WTILE;
  float* h0b  = sm + 2*WTILE;
  float* h1b  = h0b + HBUFN;

  const int tid = threadIdx.x;
  const int kk  = tid & 31;
  const int r4  = (tid >> 5) * 4;
  const int brow0 = blockIdx.x * 32;

  // small per-thread constants (biases, Wih0 column, fc) in registers
  float b0e[4][2], wx0[4][2], b1e[4][2], b0d[4][2], b1d[4][2];
  #pragma unroll
  for (int t=0;t<4;t++)
    #pragma unroll
    for (int kh=0;kh<2;kh++){
      int j = t*64 + kk + kh*32;
      b0e[t][kh] = ebih0[j] + ebhh0[j];
      wx0[t][kh] = eWih0[j];                 // Wih0 is [256][1]
      b1e[t][kh] = ebih1[j] + ebhh1[j];
      b0d[t][kh] = dbih0[j] + dbhh0[j];
      b1d[t][kh] = dbih1[j] + dbhh1[j];
    }
  const float fcw0 = fcW[kk];
  const float fcw1 = fcW[kk+32];
  const float fb   = fcb[0];

  // zero h0b,h1b (contiguous)
  for (int i=tid; i<2*HBUFN; i+=NT) h0b[i] = 0.0f;

  // prologue: Whh0 -> bufA
  #pragma unroll
  for (int i=0;i<16;i++){
    int g = (i<<8) + tid;
    float4 v = *reinterpret_cast<const float4*>(eWhh0 + g*4);
    *reinterpret_cast<float4*>(bufA + (g>>4)*MP + (g&15)*4) = v;
  }

  float xv[4];
  #pragma unroll
  for (int ri=0;ri<4;ri++) xv[ri] = x[(size_t)(brow0+r4+ri)*TT];

  float c0[4][2] = {{0.f,0.f},{0.f,0.f},{0.f,0.f},{0.f,0.f}};
  float c1[4][2] = {{0.f,0.f},{0.f,0.f},{0.f,0.f},{0.f,0.f}};
  __syncthreads();

  float* W1p = bufA;   // tile used by phase 1 (holds Whh0 at entry)
  float* W2p = bufB;

  // ---------------- encoder: 336 steps, layers 0+1 fused ----------------
  for (int t=0;t<TT;t++){
    float4 st[8];
    // phase 1: layer0  gates0 = b + x*wx + h0 @ Whh0   (uses W1p, stages Wih1->W2p)
    float a0[4][4][2];
    #pragma unroll
    for (int tt=0;tt<4;tt++)
      #pragma unroll
      for (int ri=0;ri<4;ri++)
        #pragma unroll
        for (int kh=0;kh<2;kh++)
          a0[tt][ri][kh] = fmaf(wx0[tt][kh], xv[ri], b0e[tt][kh]);

    float xn[4] = {0.f,0.f,0.f,0.f};
    if (t+1 < TT){
      #pragma unroll
      for (int ri=0;ri<4;ri++)
        xn[ri] = x[(size_t)(brow0+r4+ri)*TT + (t+1)];
    }

    stage8_issue(eWih1, tid, 0, st);
    mm32(W1p, h0b, kk, r4, a0, 0);
    stage8_write(W2p, tid, 0, st);
    stage8_issue(eWih1, tid, 8, st);
    mm32(W1p, h0b, kk, r4, a0, 32);
    stage8_write(W2p, tid, 8, st);
    __syncthreads();

    float h0v[4][2];
    lstm_update(a0, c0, h0v);
    hwrite(h0b, r4, kk, h0v);
    __syncthreads();

    // phase 2: layer1 x-part  gates1 = b1 + h0_new @ Wih1  (uses W2p, stages Whh1->W1p)
    float a1[4][4][2];
    acc_init(a1, b1e);
    stage8_issue(eWhh1, tid, 0, st);
    mm32(W2p, h0b, kk, r4, a1, 0);
    stage8_write(W1p, tid, 0, st);
    stage8_issue(eWhh1, tid, 8, st);
    mm32(W2p, h0b, kk, r4, a1, 32);
    stage8_write(W1p, tid, 8, st);
    __syncthreads();

    // phase 3: layer1 h-part  gates1 += h1_prev @ Whh1  (uses W1p, stages next->W2p)
    const float* nxt = (t+1 < TT) ? eWhh0 : dWih0;
    stage8_issue(nxt, tid, 0, st);
    mm32(W1p, h1b, kk, r4, a1, 0);
    stage8_write(W2p, tid, 0, st);
    stage8_issue(nxt, tid, 8, st);
    mm32(W1p, h1b, kk, r4, a1, 32);
    stage8_write(W2p, tid, 8, st);
    __syncthreads();

    float h1v[4][2];
    lstm_update(a1, c1, h1v);
    hwrite(h1b, r4, kk, h1v);
    // no barrier needed here: next reader of h1b is phase 3 of t+1 (>=1 barrier away)

    #pragma unroll
    for (int ri=0;ri<4;ri++) xv[ri] = xn[ri];
    float* tmp = W1p; W1p = W2p; W2p = tmp;
  }

  // ---------------- decoder: 168 autoregressive steps ----------------
  // Here W1p holds dWih0 (staged by encoder's last phase 3).
  for (int s=0;s<HZN;s++){
    float4 st[8];
    // phase A: gates0 = b0 + xin @ Wih0, xin = h1(s-1) (zero at s=0 -> skip mm)
    float a0[4][4][2];
    acc_init(a0, b0d);
    stage8_issue(dWhh0, tid, 0, st);
    if (s>0) mm32(W1p, h1b, kk, r4, a0, 0);
    stage8_write(W2p, tid, 0, st);
    stage8_issue(dWhh0, tid, 8, st);
    if (s>0) mm32(W1p, h1b, kk, r4, a0, 32);
    stage8_write(W2p, tid, 8, st);
    __syncthreads();

    // phase B: gates0 += h0 @ Whh0
    stage8_issue(dWih1, tid, 0, st);
    mm32(W2p, h0b, kk, r4, a0, 0);
    stage8_write(W1p, tid, 0, st);
    stage8_issue(dWih1, tid, 8, st);
    mm32(W2p, h0b, kk, r4, a0, 32);
    stage8_write(W1p, tid, 8, st);
    __syncthreads();

    float h0v[4][2];
    lstm_update(a0, c0, h0v);
    hwrite(h0b, r4, kk, h0v);
    __syncthreads();

    // phase C: gates1 = b1 + h0_new @ Wih1
    float a1[4][4][2];
    acc_init(a1, b1d);
    stage8_issue(dWhh1, tid, 0, st);
    mm32(W1p, h0b, kk, r4, a1, 0);
    stage8_write(W2p, tid, 0, st);
    stage8_issue(dWhh1, tid, 8, st);
    mm32(W1p, h0b, kk, r4, a1, 32);
    stage8_write(W2p, tid, 8, st);
    __syncthreads();

    // phase D: gates1 += h1_prev @ Whh1  (stages next step's Wih0 -> W1p)
    stage8_issue(dWih0, tid, 0, st);
    mm32(W2p, h1b, kk, r4, a1, 0);
    stage8_write(W1p, tid, 0, st);
    stage8_issue(dWih0, tid, 8, st);
    mm32(W2p, h1b, kk, r4, a1, 32);
    stage8_write(W1p, tid, 8, st);
    __syncthreads();

    float h1v[4][2];
    lstm_update(a1, c1, h1v);
    hwrite(h1b, r4, kk, h1v);

    // fc: pred[r] = sum_k h1[r][k]*fcW[k] + fcb  (reduce over the 32 kk lanes)
    float pr[4];
    #pragma unroll
    for (int ri=0;ri<4;ri++){
      float p = fmaf(h1v[ri][0], fcw0, h1v[ri][1]*fcw1);
      #pragma unroll
      for (int m=16;m>=1;m>>=1) p += __shfl_xor(p, m, 32);
      pr[ri] = p;
    }
    if (kk == 0){
      #pragma unroll
      for (int ri=0;ri<4;ri++)
        out[(size_t)(brow0+r4+ri)*HZN + s] = pr[ri] + fb;
    }
    __syncthreads();   // h1b visible for phase A of s+1
  }
}

extern "C" void kernel_launch(void* const* d_in, const int* in_sizes, int n_in,
                              void* d_out, int out_size, void* d_ws, size_t ws_size,
                              hipStream_t stream)
{
  (void)in_sizes; (void)n_in; (void)d_ws; (void)ws_size; (void)out_size;
  const float* x     = (const float*)d_in[0];
  const float* eWih0 = (const float*)d_in[1];
  const float* eWhh0 = (const float*)d_in[2];
  const float* ebih0 = (const float*)d_in[3];
  const float* ebhh0 = (const float*)d_in[4];
  const float* eWih1 = (const float*)d_in[5];
  const float* eWhh1 = (const float*)d_in[6];
  const float* ebih1 = (const float*)d_in[7];
  const float* ebhh1 = (const float*)d_in[8];
  const float* dWih0 = (const float*)d_in[9];
  const float* dWhh0 = (const float*)d_in[10];
  const float* dbih0 = (const float*)d_in[11];
  const float* dbhh0 = (const float*)d_in[12];
  const float* dWih1 = (const float*)d_in[13];
  const float* dWhh1 = (const float*)d_in[14];
  const float* dbih1 = (const float*)d_in[15];
  const float* dbhh1 = (const float*)d_in[16];
  const float* fcW   = (const float*)d_in[17];
  const float* fcb   = (const float*)d_in[18];
  float* out = (float*)d_out;

  const int lds_bytes = (2*WTILE + 2*HBUFN) * 4;   // 156,672 B
  hipFuncSetAttribute((const void*)edlstm_kernel,
                      hipFuncAttributeMaxDynamicSharedMemorySize, lds_bytes);
  edlstm_kernel<<<dim3(NB), dim3(NT), lds_bytes, stream>>>(
      x, eWih0, eWhh0, ebih0, ebhh0, eWih1, eWhh1, ebih1, ebhh1,
      dWih0, dWhh0, dbih0, dbhh0, dWih1, dWhh1, dbih1, dbhh1,
      fcW, fcb, out);
}